// Round 17
// baseline (491.623 us; speedup 1.0000x reference)
//
#include <hip/hip_runtime.h>

#define N_NODES 100000
#define N_EDGES 1600000
#define IN_F 256
#define HID 128
#define OUT_F 48
#define PAD_F 64
#define ALPHA 0.01f
#define K_STEPS 10
#define DROP_SCALE (1.0f / (1.0f + 1e-5f))

#define NBUCK 196      // buckets of 512 rows
#define BCAP 10240     // bucket capacity (mean 8163, 23 sigma headroom)
#define EPB 4096       // edges per bucketing block
#define ROW_MASK_CLR 0xFFFFFFFFFC01FFFFULL  // clears bits 25:17 (local row)

#define BUCKET_BLOCKS 391   // ceil(1.6M / 4096)
#define CONVW_BLOCKS 153    // (32768 + 6144 + 255)/256
#define MLP2_BLOCKS 391     // ceil(100000 / 256), 256 rows per 1024-thr block

typedef __bf16 v8bf __attribute__((ext_vector_type(8)));
typedef float v4f __attribute__((ext_vector_type(4)));
typedef unsigned long long u64;

static __device__ __forceinline__ __bf16 tobf(float f) { return (__bf16)f; }

// ---------------- dispatch 1: bucket binning + weight conv ------------------
// rec u64: val[63:32] | localrow[25:17] | col[16:0]
__global__ __launch_bounds__(256) void pre_kernel(
    const float* __restrict__ W1, const float* __restrict__ W2,
    __bf16* __restrict__ w1t, __bf16* __restrict__ w2t,
    const int* __restrict__ rows, const int* __restrict__ cols,
    const float* __restrict__ vals, int* __restrict__ bcur,
    u64* __restrict__ brec) {
  __shared__ int lhist[NBUCK];
  __shared__ int lbase[NBUCK];
  const int tid = threadIdx.x;

  if (blockIdx.x < BUCKET_BLOCKS) {
    const int base = blockIdx.x * EPB;

    for (int i = tid; i < NBUCK; i += 256) lhist[i] = 0;
    __syncthreads();

    u64 rec[16];
    short bb[16];
    short pp[16];
#pragma unroll
    for (int j = 0; j < 4; j++) {
      int e = base + j * 1024 + tid * 4;
      bool ok = e < N_EDGES;
      int4 r4 = ok ? *(const int4*)(rows + e) : make_int4(0, 0, 0, 0);
      int4 c4 = ok ? *(const int4*)(cols + e) : make_int4(0, 0, 0, 0);
      float4 v4 = ok ? *(const float4*)(vals + e) : make_float4(0, 0, 0, 0);
      int rr[4] = {r4.x, r4.y, r4.z, r4.w};
      int cc[4] = {c4.x, c4.y, c4.z, c4.w};
      float vv[4] = {v4.x, v4.y, v4.z, v4.w};
#pragma unroll
      for (int q = 0; q < 4; q++) {
        int idx = j * 4 + q;
        int b = rr[q] >> 9;
        float v = vv[q] * (DROP_SCALE * (1.0f - ALPHA));
        rec[idx] = ((u64)__float_as_uint(v) << 32) |
                   ((u64)(rr[q] & 511) << 17) | (unsigned)cc[q];
        bb[idx] = ok ? (short)b : (short)-1;
        pp[idx] = ok ? (short)atomicAdd(&lhist[b], 1) : (short)0;
      }
    }
    __syncthreads();

    for (int i = tid; i < NBUCK; i += 256) {
      int n = lhist[i];
      lbase[i] = (n > 0) ? atomicAdd(&bcur[i * 16], n) : 0;
    }
    __syncthreads();

#pragma unroll
    for (int j = 0; j < 16; j++) {
      if (bb[j] >= 0)
        brec[(size_t)bb[j] * BCAP + lbase[bb[j]] + pp[j]] = rec[j];
    }
  } else {
    // ---- weight transpose+convert ----
    int i = (blockIdx.x - BUCKET_BLOCKS) * 256 + tid;
    if (i < HID * IN_F) {
      int n = i >> 8, k = i & 255;
      w1t[i] = tobf(W1[k * HID + n]);
    }
    int j = i - HID * IN_F;
    if (j >= 0 && j < OUT_F * HID) {
      int n = j >> 7, k = j & 127;
      w2t[j] = tobf(W2[k * OUT_F + n]);
    }
  }
}

// ---------------- dispatch 2: MLP (1024 thr, asm-issued x prefetch) + CSR ---
// 16 waves x 16 rows = 256 rows per block; w1+w2 staged ONCE per block.
// x row loaded via inline-asm global_load_dwordx4: issued before staging,
// unsinkable, registers pinned (52+64=116 VGPR <= 128 @ 4 waves/SIMD).
__global__ __launch_bounds__(1024, 1) void fused_mlp_csr(
    const float* __restrict__ x, const __bf16* __restrict__ w1t,
    const float* __restrict__ b1, const __bf16* __restrict__ w2t,
    const float* __restrict__ b2, __bf16* __restrict__ h0,
    const int* __restrict__ bcur, const u64* __restrict__ brec,
    int* __restrict__ rowptr, u64* __restrict__ edges) {
  __shared__ __bf16 w1s[128][264];  // 67.6 KB (full W1^T, +8 pad)
  __shared__ __bf16 h1s[256][136];  // 69.6 KB
  __shared__ __bf16 w2s[48][136];   // 13.1 KB
  __shared__ int bs[256];
  __shared__ int cnt[512];
  __shared__ int sc[512];
  // total ~152 KB -> 1 block/CU

  const int tid = threadIdx.x;

  if (blockIdx.x < MLP2_BLOCKS) {
    // ======================= MLP path =======================
    const int wv = tid >> 6;          // 0..15
    const int l = tid & 63;
    const int lm = l & 15;
    const int ko = (l >> 4) * 8;
    const int n0 = blockIdx.x * 256;
    const int nw = n0 + wv * 16;
    const int xrow = nw + lm;
    const int xrc = (xrow < N_NODES) ? xrow : (N_NODES - 1);  // clamp ragged
    const float* xrp = x + (size_t)xrc * IN_F + ko;

    // issue this lane's full x row as 8 asm load-pairs (16 x dwordx4),
    // back-to-back, BEFORE the staging loop. Asm outputs cannot be sunk.
    v4f xf[16];
#pragma unroll
    for (int k0 = 0; k0 < 8; k0++) {
      asm volatile(
          "global_load_dwordx4 %0, %2, off\n\t"
          "global_load_dwordx4 %1, %2, off offset:16"
          : "=&v"(xf[2 * k0]), "=&v"(xf[2 * k0 + 1])
          : "v"(xrp + k0 * 32));
    }

    // stage full w1t (4096 x 16B) + w2t (768 x 16B) once per block;
    // x-load latency hides under this ~80 KB fill.
    const uint4* w1src = (const uint4*)w1t;
    for (int i = tid; i < 4096; i += 1024)
      *(uint4*)&w1s[i >> 5][(i & 31) * 8] = w1src[i];
    const uint4* w2src = (const uint4*)w2t;
    for (int i = tid; i < 768; i += 1024)
      *(uint4*)&w2s[i >> 4][(i & 15) * 8] = w2src[i];
    __syncthreads();

    // drain our asm loads before use; fence consumer scheduling (rule #18)
    asm volatile("s_waitcnt vmcnt(0)" ::: "memory");
    __builtin_amdgcn_sched_barrier(0);

    // convert fp32 -> bf16 A-frags
    v8bf a8[8];
#pragma unroll
    for (int k0 = 0; k0 < 8; k0++) {
#pragma unroll
      for (int j = 0; j < 8; j++) a8[k0][j] = tobf(xf[2 * k0 + (j >> 2)][j & 3]);
    }

    // layer 1: per wave [16 x 256] @ [256 x 128], B from LDS
    v4f acc1[8];
#pragma unroll
    for (int nf = 0; nf < 8; nf++) acc1[nf] = (v4f){0.f, 0.f, 0.f, 0.f};
#pragma unroll
    for (int k0 = 0; k0 < 8; k0++) {
#pragma unroll
      for (int nf = 0; nf < 8; nf++) {
        v8bf b = *(const v8bf*)&w1s[nf * 16 + lm][k0 * 32 + ko];
        acc1[nf] = __builtin_amdgcn_mfma_f32_16x16x32_bf16(a8[k0], b, acc1[nf], 0, 0, 0);
      }
    }

    // bias + relu -> h1s. D frag: col=lm, row=(l>>4)*4+q
#pragma unroll
    for (int nf = 0; nf < 8; nf++) {
      float bb = b1[nf * 16 + lm];
#pragma unroll
      for (int q = 0; q < 4; q++) {
        int rr = wv * 16 + (l >> 4) * 4 + q;
        h1s[rr][nf * 16 + lm] = tobf(fmaxf(acc1[nf][q] + bb, 0.f));
      }
    }
    __syncthreads();

    // layer 2: A from h1s, B from w2s (LDS)
    const int lrow = wv * 16 + lm;
    v4f acc2[3];
#pragma unroll
    for (int nf = 0; nf < 3; nf++) acc2[nf] = (v4f){0.f, 0.f, 0.f, 0.f};
#pragma unroll
    for (int k0 = 0; k0 < 4; k0++) {
      v8bf a = *(const v8bf*)&h1s[lrow][k0 * 32 + ko];
#pragma unroll
      for (int nf = 0; nf < 3; nf++) {
        v8bf b = *(const v8bf*)&w2s[nf * 16 + lm][k0 * 32 + ko];
        acc2[nf] = __builtin_amdgcn_mfma_f32_16x16x32_bf16(a, b, acc2[nf], 0, 0, 0);
      }
    }
#pragma unroll
    for (int nf = 0; nf < 3; nf++) {
      float bb = b2[nf * 16 + lm];
#pragma unroll
      for (int q = 0; q < 4; q++) {
        int node = nw + (l >> 4) * 4 + q;
        if (node < N_NODES)
          h0[(size_t)node * PAD_F + nf * 16 + lm] = tobf(acc2[nf][q] + bb);
      }
    }
    // zero pad cols 48..63: 256 rows x 4 uint2 chunks = 1024 = blockDim
    {
      int row = tid >> 2, chunk = tid & 3;
      int node = n0 + row;
      if (node < N_NODES) {
        uint2 z = make_uint2(0, 0);
        *(uint2*)(h0 + (size_t)node * PAD_F + 48 + chunk * 4) = z;
      }
    }
  } else {
    // ======================= CSR path (1024 thr) =======================
    const int b = blockIdx.x - MLP2_BLOCKS;
    const int t = tid;

    // inline exclusive prefix over bucket counts (196 entries, t<256 active)
    if (t < 256) bs[t] = (t < NBUCK) ? bcur[t * 16] : 0;
    __syncthreads();
    for (int off = 1; off < 256; off <<= 1) {
      int add = (t < 256 && t >= off) ? bs[t - off] : 0;
      __syncthreads();
      if (t < 256) bs[t] += add;
      __syncthreads();
    }
    const int n = bcur[b * 16];
    const int base = bs[b] - n;  // exclusive
    const size_t boff = (size_t)b * BCAP;
    if (b == 0 && t == 0) rowptr[N_NODES] = N_EDGES;

    if (t < 512) cnt[t] = 0;
    __syncthreads();
    for (int i = t; i < n; i += 1024)
      atomicAdd(&cnt[(int)((brec[boff + i] >> 17) & 511)], 1);
    __syncthreads();

    int v = (t < 512) ? cnt[t] : 0;
    if (t < 512) sc[t] = v;
    __syncthreads();
    for (int off = 1; off < 512; off <<= 1) {
      int add = (t < 512 && t >= off) ? sc[t - off] : 0;
      __syncthreads();
      if (t < 512) sc[t] += add;
      __syncthreads();
    }
    if (t < 512) {
      int excl = sc[t] - v;
      int grow = b * 512 + t;
      if (grow < N_NODES) rowptr[grow] = base + excl;
      cnt[t] = excl;
    }
    __syncthreads();

    for (int i = t; i < n; i += 1024) {
      u64 rec = brec[boff + i];
      int rr = (int)((rec >> 17) & 511);
      int p = atomicAdd(&cnt[rr], 1);
      edges[base + p] = rec & ROW_MASK_CLR;
    }
  }
}

// ---------------- propagation: wave/row, 8 edges x 8 lanes (dwordx4) -------
template <int FINAL>
__global__ __launch_bounds__(256) void prop_kernel(
    const __bf16* __restrict__ hin, __bf16* __restrict__ hout,
    float* __restrict__ fout, const int* __restrict__ rowptr,
    const u64* __restrict__ edges) {
  int wid = (blockIdx.x * 256 + threadIdx.x) >> 6;
  int lane = threadIdx.x & 63;
  if (wid >= N_NODES) return;
  const int g = lane >> 3;
  const int t = lane & 7;
  int s = __builtin_amdgcn_readfirstlane(rowptr[wid]);
  int e = __builtin_amdgcn_readfirstlane(rowptr[wid + 1]);

  float acc[8];
#pragma unroll
  for (int j = 0; j < 8; j++) acc[j] = 0.f;

  if (g == 0) {
    uint4 q = *(const uint4*)(hin + (size_t)wid * PAD_F + t * 8);
    unsigned uu[4] = {q.x, q.y, q.z, q.w};
#pragma unroll
    for (int k = 0; k < 4; k++) {
      acc[2 * k] = ALPHA * __uint_as_float(uu[k] << 16);
      acc[2 * k + 1] = ALPHA * __uint_as_float(uu[k] & 0xffff0000u);
    }
  }

  int i = s + g;
  for (; i + 8 < e; i += 16) {
    u64 r0 = edges[i];
    u64 r1 = edges[i + 8];
    int c0 = (int)(r0 & 0xffffffffu);
    int c1 = (int)(r1 & 0xffffffffu);
    float v0 = __uint_as_float((unsigned)(r0 >> 32));
    float v1 = __uint_as_float((unsigned)(r1 >> 32));
    uint4 q0 = *(const uint4*)(hin + (size_t)c0 * PAD_F + t * 8);
    uint4 q1 = *(const uint4*)(hin + (size_t)c1 * PAD_F + t * 8);
    unsigned a0[4] = {q0.x, q0.y, q0.z, q0.w};
    unsigned a1[4] = {q1.x, q1.y, q1.z, q1.w};
#pragma unroll
    for (int k = 0; k < 4; k++) {
      acc[2 * k] = fmaf(v0, __uint_as_float(a0[k] << 16), acc[2 * k]);
      acc[2 * k + 1] = fmaf(v0, __uint_as_float(a0[k] & 0xffff0000u), acc[2 * k + 1]);
    }
#pragma unroll
    for (int k = 0; k < 4; k++) {
      acc[2 * k] = fmaf(v1, __uint_as_float(a1[k] << 16), acc[2 * k]);
      acc[2 * k + 1] = fmaf(v1, __uint_as_float(a1[k] & 0xffff0000u), acc[2 * k + 1]);
    }
  }
  if (i < e) {
    u64 r0 = edges[i];
    int c0 = (int)(r0 & 0xffffffffu);
    float v0 = __uint_as_float((unsigned)(r0 >> 32));
    uint4 q0 = *(const uint4*)(hin + (size_t)c0 * PAD_F + t * 8);
    unsigned a0[4] = {q0.x, q0.y, q0.z, q0.w};
#pragma unroll
    for (int k = 0; k < 4; k++) {
      acc[2 * k] = fmaf(v0, __uint_as_float(a0[k] << 16), acc[2 * k]);
      acc[2 * k + 1] = fmaf(v0, __uint_as_float(a0[k] & 0xffff0000u), acc[2 * k + 1]);
    }
  }

#pragma unroll
  for (int m = 8; m <= 32; m <<= 1) {
#pragma unroll
    for (int j = 0; j < 8; j++) acc[j] += __shfl_xor(acc[j], m, 64);
  }

  if (g == 0) {
    if (FINAL) {
      if (t < 6) {
        float* dst = fout + (size_t)wid * OUT_F + t * 8;
        v4f lo4 = {acc[0], acc[1], acc[2], acc[3]};
        v4f hi4 = {acc[4], acc[5], acc[6], acc[7]};
        __builtin_nontemporal_store(lo4, (v4f*)dst);
        __builtin_nontemporal_store(hi4, (v4f*)(dst + 4));
      }
    } else {
      unsigned w[4];
#pragma unroll
      for (int k = 0; k < 4; k++) {
        unsigned short lo = __builtin_bit_cast(unsigned short, (__bf16)acc[2 * k]);
        unsigned short hi = __builtin_bit_cast(unsigned short, (__bf16)acc[2 * k + 1]);
        w[k] = ((unsigned)hi << 16) | lo;
      }
      *(uint4*)(hout + (size_t)wid * PAD_F + t * 8) =
          make_uint4(w[0], w[1], w[2], w[3]);
    }
  }
}

// ---------------- launch ----------------------------------------------------
extern "C" void kernel_launch(void* const* d_in, const int* in_sizes, int n_in,
                              void* d_out, int out_size, void* d_ws,
                              size_t ws_size, hipStream_t stream) {
  const float* x = (const float*)d_in[0];
  const int* rows = (const int*)d_in[1];
  const int* cols = (const int*)d_in[2];
  const float* vals = (const float*)d_in[3];
  const float* W1 = (const float*)d_in[4];
  const float* b1 = (const float*)d_in[5];
  const float* W2 = (const float*)d_in[6];
  const float* b2 = (const float*)d_in[7];
  float* out = (float*)d_out;

  char* ws = (char*)d_ws;
  const size_t HB_OFF = 0;                  // 12,800,000
  const size_t HA_OFF = 12800000;           // 12,800,000
  const size_t EDGES_OFF = 25600000;        // 12,800,000
  const size_t BREC_OFF = 38400000;         // 16,056,320
  const size_t ROWPTR_OFF = 54456320;       // 400,128
  const size_t BCUR_OFF = 54856448;         // 12,544
  const size_t W1T_OFF = 54870016;          // 65,536
  const size_t W2T_OFF = 54935552;          // 12,288  -> end 54,947,840

  __bf16* hA = (__bf16*)(ws + HA_OFF);
  __bf16* hB = (__bf16*)(ws + HB_OFF);
  u64* edges = (u64*)(ws + EDGES_OFF);
  u64* brec = (u64*)(ws + BREC_OFF);
  int* rowptr = (int*)(ws + ROWPTR_OFF);
  int* bcur = (int*)(ws + BCUR_OFF);
  __bf16* w1t = (__bf16*)(ws + W1T_OFF);
  __bf16* w2t = (__bf16*)(ws + W2T_OFF);

  (void)hipMemsetAsync(bcur, 0, NBUCK * 64, stream);

  pre_kernel<<<BUCKET_BLOCKS + CONVW_BLOCKS, 256, 0, stream>>>(
      W1, W2, w1t, w2t, rows, cols, vals, bcur, brec);

  fused_mlp_csr<<<MLP2_BLOCKS + NBUCK, 1024, 0, stream>>>(
      x, w1t, b1, w2t, b2, hA, bcur, brec, rowptr, edges);

  const int PROP_BLOCKS = (N_NODES * 64 + 255) / 256;
  for (int k = 0; k < K_STEPS - 1; k++) {
    const __bf16* hin = (k & 1) ? hB : hA;
    __bf16* hout = (k & 1) ? hA : hB;
    prop_kernel<0><<<PROP_BLOCKS, 256, 0, stream>>>(hin, hout, nullptr, rowptr,
                                                    edges);
  }
  prop_kernel<1><<<PROP_BLOCKS, 256, 0, stream>>>(hB, nullptr, out, rowptr,
                                                  edges);
}

// Round 18
// 491.339 us; speedup vs baseline: 1.0006x; 1.0006x over previous
//
#include <hip/hip_runtime.h>

#define N_NODES 100000
#define N_EDGES 1600000
#define IN_F 256
#define HID 128
#define OUT_F 48
#define PAD_F 64
#define ALPHA 0.01f
#define K_STEPS 10
#define DROP_SCALE (1.0f / (1.0f + 1e-5f))

#define NBUCK 196      // buckets of 512 rows
#define BCAP 10240     // bucket capacity (mean 8163, 23 sigma headroom)
#define EPB 4096       // edges per bucketing block
#define ROW_MASK_CLR 0xFFFFFFFFFC01FFFFULL  // clears bits 25:17 (local row)

#define BUCKET_BLOCKS 391   // ceil(1.6M / 4096)
#define CONVW_BLOCKS 153    // (32768 + 6144 + 255)/256
#define MLP2_BLOCKS 391     // ceil(100000 / 256), 256 rows per 1024-thr block

typedef __bf16 v8bf __attribute__((ext_vector_type(8)));
typedef float v4f __attribute__((ext_vector_type(4)));
typedef unsigned long long u64;

static __device__ __forceinline__ __bf16 tobf(float f) { return (__bf16)f; }

// ---------------- dispatch 1: bucket binning + weight conv ------------------
// rec u64: val[63:32] | localrow[25:17] | col[16:0]
__global__ __launch_bounds__(256) void pre_kernel(
    const float* __restrict__ W1, const float* __restrict__ W2,
    __bf16* __restrict__ w1t, __bf16* __restrict__ w2t,
    const int* __restrict__ rows, const int* __restrict__ cols,
    const float* __restrict__ vals, int* __restrict__ bcur,
    u64* __restrict__ brec) {
  __shared__ int lhist[NBUCK];
  __shared__ int lbase[NBUCK];
  const int tid = threadIdx.x;

  if (blockIdx.x < BUCKET_BLOCKS) {
    const int base = blockIdx.x * EPB;

    for (int i = tid; i < NBUCK; i += 256) lhist[i] = 0;
    __syncthreads();

    u64 rec[16];
    short bb[16];
    short pp[16];
#pragma unroll
    for (int j = 0; j < 4; j++) {
      int e = base + j * 1024 + tid * 4;
      bool ok = e < N_EDGES;
      int4 r4 = ok ? *(const int4*)(rows + e) : make_int4(0, 0, 0, 0);
      int4 c4 = ok ? *(const int4*)(cols + e) : make_int4(0, 0, 0, 0);
      float4 v4 = ok ? *(const float4*)(vals + e) : make_float4(0, 0, 0, 0);
      int rr[4] = {r4.x, r4.y, r4.z, r4.w};
      int cc[4] = {c4.x, c4.y, c4.z, c4.w};
      float vv[4] = {v4.x, v4.y, v4.z, v4.w};
#pragma unroll
      for (int q = 0; q < 4; q++) {
        int idx = j * 4 + q;
        int b = rr[q] >> 9;
        float v = vv[q] * (DROP_SCALE * (1.0f - ALPHA));
        rec[idx] = ((u64)__float_as_uint(v) << 32) |
                   ((u64)(rr[q] & 511) << 17) | (unsigned)cc[q];
        bb[idx] = ok ? (short)b : (short)-1;
        pp[idx] = ok ? (short)atomicAdd(&lhist[b], 1) : (short)0;
      }
    }
    __syncthreads();

    for (int i = tid; i < NBUCK; i += 256) {
      int n = lhist[i];
      lbase[i] = (n > 0) ? atomicAdd(&bcur[i * 16], n) : 0;
    }
    __syncthreads();

#pragma unroll
    for (int j = 0; j < 16; j++) {
      if (bb[j] >= 0)
        brec[(size_t)bb[j] * BCAP + lbase[bb[j]] + pp[j]] = rec[j];
    }
  } else {
    // ---- weight transpose+convert ----
    int i = (blockIdx.x - BUCKET_BLOCKS) * 256 + tid;
    if (i < HID * IN_F) {
      int n = i >> 8, k = i & 255;
      w1t[i] = tobf(W1[k * HID + n]);
    }
    int j = i - HID * IN_F;
    if (j >= 0 && j < OUT_F * HID) {
      int n = j >> 7, k = j & 127;
      w2t[j] = tobf(W2[k * OUT_F + n]);
    }
  }
}

// ---------------- dispatch 2: MLP (1024 thr, pinned x prefetch) + CSR -------
// 16 waves x 16 rows = 256 rows per block; w1+w2 staged ONCE per block.
// x row loaded via inline-asm global_load_dwordx4 WITH "memory" clobber:
// unmovable across the LDS staging stores -> issued first, 64 VGPRs live
// across the fill (52+64=116 <= 128 @ 4 waves/SIMD).
__global__ __launch_bounds__(1024, 1) void fused_mlp_csr(
    const float* __restrict__ x, const __bf16* __restrict__ w1t,
    const float* __restrict__ b1, const __bf16* __restrict__ w2t,
    const float* __restrict__ b2, __bf16* __restrict__ h0,
    const int* __restrict__ bcur, const u64* __restrict__ brec,
    int* __restrict__ rowptr, u64* __restrict__ edges) {
  __shared__ __bf16 w1s[128][264];  // 67.6 KB (full W1^T, +8 pad)
  __shared__ __bf16 h1s[256][136];  // 69.6 KB
  __shared__ __bf16 w2s[48][136];   // 13.1 KB
  __shared__ int bs[256];
  __shared__ int cnt[512];
  __shared__ int sc[512];
  // total ~152 KB -> 1 block/CU

  const int tid = threadIdx.x;

  if (blockIdx.x < MLP2_BLOCKS) {
    // ======================= MLP path =======================
    const int wv = tid >> 6;          // 0..15
    const int l = tid & 63;
    const int lm = l & 15;
    const int ko = (l >> 4) * 8;
    const int n0 = blockIdx.x * 256;
    const int nw = n0 + wv * 16;
    const int xrow = nw + lm;
    const int xrc = (xrow < N_NODES) ? xrow : (N_NODES - 1);  // clamp ragged
    const float* xrp = x + (size_t)xrc * IN_F + ko;

    // issue this lane's full x row as 8 asm load-pairs (16 x dwordx4),
    // back-to-back, BEFORE the staging loop. "memory" clobber makes them
    // unmovable across the LDS stores below.
    v4f xf[16];
#pragma unroll
    for (int k0 = 0; k0 < 8; k0++) {
      asm volatile(
          "global_load_dwordx4 %0, %2, off\n\t"
          "global_load_dwordx4 %1, %2, off offset:16"
          : "=&v"(xf[2 * k0]), "=&v"(xf[2 * k0 + 1])
          : "v"(xrp + k0 * 32)
          : "memory");
    }

    // stage full w1t (4096 x 16B) + w2t (768 x 16B) once per block;
    // x-load latency hides under this ~80 KB fill.
    const uint4* w1src = (const uint4*)w1t;
    for (int i = tid; i < 4096; i += 1024)
      *(uint4*)&w1s[i >> 5][(i & 31) * 8] = w1src[i];
    const uint4* w2src = (const uint4*)w2t;
    for (int i = tid; i < 768; i += 1024)
      *(uint4*)&w2s[i >> 4][(i & 15) * 8] = w2src[i];
    __syncthreads();

    // drain our asm loads before use; fence consumer scheduling (rule #18)
    asm volatile("s_waitcnt vmcnt(0)" ::: "memory");
    __builtin_amdgcn_sched_barrier(0);

    // convert fp32 -> bf16 A-frags
    v8bf a8[8];
#pragma unroll
    for (int k0 = 0; k0 < 8; k0++) {
#pragma unroll
      for (int j = 0; j < 8; j++) a8[k0][j] = tobf(xf[2 * k0 + (j >> 2)][j & 3]);
    }

    // layer 1: per wave [16 x 256] @ [256 x 128], B from LDS
    v4f acc1[8];
#pragma unroll
    for (int nf = 0; nf < 8; nf++) acc1[nf] = (v4f){0.f, 0.f, 0.f, 0.f};
#pragma unroll
    for (int k0 = 0; k0 < 8; k0++) {
#pragma unroll
      for (int nf = 0; nf < 8; nf++) {
        v8bf b = *(const v8bf*)&w1s[nf * 16 + lm][k0 * 32 + ko];
        acc1[nf] = __builtin_amdgcn_mfma_f32_16x16x32_bf16(a8[k0], b, acc1[nf], 0, 0, 0);
      }
    }

    // bias + relu -> h1s. D frag: col=lm, row=(l>>4)*4+q
#pragma unroll
    for (int nf = 0; nf < 8; nf++) {
      float bb = b1[nf * 16 + lm];
#pragma unroll
      for (int q = 0; q < 4; q++) {
        int rr = wv * 16 + (l >> 4) * 4 + q;
        h1s[rr][nf * 16 + lm] = tobf(fmaxf(acc1[nf][q] + bb, 0.f));
      }
    }
    __syncthreads();

    // layer 2: A from h1s, B from w2s (LDS)
    const int lrow = wv * 16 + lm;
    v4f acc2[3];
#pragma unroll
    for (int nf = 0; nf < 3; nf++) acc2[nf] = (v4f){0.f, 0.f, 0.f, 0.f};
#pragma unroll
    for (int k0 = 0; k0 < 4; k0++) {
      v8bf a = *(const v8bf*)&h1s[lrow][k0 * 32 + ko];
#pragma unroll
      for (int nf = 0; nf < 3; nf++) {
        v8bf b = *(const v8bf*)&w2s[nf * 16 + lm][k0 * 32 + ko];
        acc2[nf] = __builtin_amdgcn_mfma_f32_16x16x32_bf16(a, b, acc2[nf], 0, 0, 0);
      }
    }
#pragma unroll
    for (int nf = 0; nf < 3; nf++) {
      float bb = b2[nf * 16 + lm];
#pragma unroll
      for (int q = 0; q < 4; q++) {
        int node = nw + (l >> 4) * 4 + q;
        if (node < N_NODES)
          h0[(size_t)node * PAD_F + nf * 16 + lm] = tobf(acc2[nf][q] + bb);
      }
    }
    // zero pad cols 48..63: 256 rows x 4 uint2 chunks = 1024 = blockDim
    {
      int row = tid >> 2, chunk = tid & 3;
      int node = n0 + row;
      if (node < N_NODES) {
        uint2 z = make_uint2(0, 0);
        *(uint2*)(h0 + (size_t)node * PAD_F + 48 + chunk * 4) = z;
      }
    }
  } else {
    // ======================= CSR path (1024 thr) =======================
    const int b = blockIdx.x - MLP2_BLOCKS;
    const int t = tid;

    // inline exclusive prefix over bucket counts (196 entries, t<256 active)
    if (t < 256) bs[t] = (t < NBUCK) ? bcur[t * 16] : 0;
    __syncthreads();
    for (int off = 1; off < 256; off <<= 1) {
      int add = (t < 256 && t >= off) ? bs[t - off] : 0;
      __syncthreads();
      if (t < 256) bs[t] += add;
      __syncthreads();
    }
    const int n = bcur[b * 16];
    const int base = bs[b] - n;  // exclusive
    const size_t boff = (size_t)b * BCAP;
    if (b == 0 && t == 0) rowptr[N_NODES] = N_EDGES;

    if (t < 512) cnt[t] = 0;
    __syncthreads();
    for (int i = t; i < n; i += 1024)
      atomicAdd(&cnt[(int)((brec[boff + i] >> 17) & 511)], 1);
    __syncthreads();

    int v = (t < 512) ? cnt[t] : 0;
    if (t < 512) sc[t] = v;
    __syncthreads();
    for (int off = 1; off < 512; off <<= 1) {
      int add = (t < 512 && t >= off) ? sc[t - off] : 0;
      __syncthreads();
      if (t < 512) sc[t] += add;
      __syncthreads();
    }
    if (t < 512) {
      int excl = sc[t] - v;
      int grow = b * 512 + t;
      if (grow < N_NODES) rowptr[grow] = base + excl;
      cnt[t] = excl;
    }
    __syncthreads();

    for (int i = t; i < n; i += 1024) {
      u64 rec = brec[boff + i];
      int rr = (int)((rec >> 17) & 511);
      int p = atomicAdd(&cnt[rr], 1);
      edges[base + p] = rec & ROW_MASK_CLR;
    }
  }
}

// ---------------- propagation: wave/row, 8 edges x 8 lanes (dwordx4) -------
template <int FINAL>
__global__ __launch_bounds__(256) void prop_kernel(
    const __bf16* __restrict__ hin, __bf16* __restrict__ hout,
    float* __restrict__ fout, const int* __restrict__ rowptr,
    const u64* __restrict__ edges) {
  int wid = (blockIdx.x * 256 + threadIdx.x) >> 6;
  int lane = threadIdx.x & 63;
  if (wid >= N_NODES) return;
  const int g = lane >> 3;
  const int t = lane & 7;
  int s = __builtin_amdgcn_readfirstlane(rowptr[wid]);
  int e = __builtin_amdgcn_readfirstlane(rowptr[wid + 1]);

  float acc[8];
#pragma unroll
  for (int j = 0; j < 8; j++) acc[j] = 0.f;

  if (g == 0) {
    uint4 q = *(const uint4*)(hin + (size_t)wid * PAD_F + t * 8);
    unsigned uu[4] = {q.x, q.y, q.z, q.w};
#pragma unroll
    for (int k = 0; k < 4; k++) {
      acc[2 * k] = ALPHA * __uint_as_float(uu[k] << 16);
      acc[2 * k + 1] = ALPHA * __uint_as_float(uu[k] & 0xffff0000u);
    }
  }

  int i = s + g;
  for (; i + 8 < e; i += 16) {
    u64 r0 = edges[i];
    u64 r1 = edges[i + 8];
    int c0 = (int)(r0 & 0xffffffffu);
    int c1 = (int)(r1 & 0xffffffffu);
    float v0 = __uint_as_float((unsigned)(r0 >> 32));
    float v1 = __uint_as_float((unsigned)(r1 >> 32));
    uint4 q0 = *(const uint4*)(hin + (size_t)c0 * PAD_F + t * 8);
    uint4 q1 = *(const uint4*)(hin + (size_t)c1 * PAD_F + t * 8);
    unsigned a0[4] = {q0.x, q0.y, q0.z, q0.w};
    unsigned a1[4] = {q1.x, q1.y, q1.z, q1.w};
#pragma unroll
    for (int k = 0; k < 4; k++) {
      acc[2 * k] = fmaf(v0, __uint_as_float(a0[k] << 16), acc[2 * k]);
      acc[2 * k + 1] = fmaf(v0, __uint_as_float(a0[k] & 0xffff0000u), acc[2 * k + 1]);
    }
#pragma unroll
    for (int k = 0; k < 4; k++) {
      acc[2 * k] = fmaf(v1, __uint_as_float(a1[k] << 16), acc[2 * k]);
      acc[2 * k + 1] = fmaf(v1, __uint_as_float(a1[k] & 0xffff0000u), acc[2 * k + 1]);
    }
  }
  if (i < e) {
    u64 r0 = edges[i];
    int c0 = (int)(r0 & 0xffffffffu);
    float v0 = __uint_as_float((unsigned)(r0 >> 32));
    uint4 q0 = *(const uint4*)(hin + (size_t)c0 * PAD_F + t * 8);
    unsigned a0[4] = {q0.x, q0.y, q0.z, q0.w};
#pragma unroll
    for (int k = 0; k < 4; k++) {
      acc[2 * k] = fmaf(v0, __uint_as_float(a0[k] << 16), acc[2 * k]);
      acc[2 * k + 1] = fmaf(v0, __uint_as_float(a0[k] & 0xffff0000u), acc[2 * k + 1]);
    }
  }

#pragma unroll
  for (int m = 8; m <= 32; m <<= 1) {
#pragma unroll
    for (int j = 0; j < 8; j++) acc[j] += __shfl_xor(acc[j], m, 64);
  }

  if (g == 0) {
    if (FINAL) {
      if (t < 6) {
        float* dst = fout + (size_t)wid * OUT_F + t * 8;
        v4f lo4 = {acc[0], acc[1], acc[2], acc[3]};
        v4f hi4 = {acc[4], acc[5], acc[6], acc[7]};
        __builtin_nontemporal_store(lo4, (v4f*)dst);
        __builtin_nontemporal_store(hi4, (v4f*)(dst + 4));
      }
    } else {
      unsigned w[4];
#pragma unroll
      for (int k = 0; k < 4; k++) {
        unsigned short lo = __builtin_bit_cast(unsigned short, (__bf16)acc[2 * k]);
        unsigned short hi = __builtin_bit_cast(unsigned short, (__bf16)acc[2 * k + 1]);
        w[k] = ((unsigned)hi << 16) | lo;
      }
      *(uint4*)(hout + (size_t)wid * PAD_F + t * 8) =
          make_uint4(w[0], w[1], w[2], w[3]);
    }
  }
}

// ---------------- launch ----------------------------------------------------
extern "C" void kernel_launch(void* const* d_in, const int* in_sizes, int n_in,
                              void* d_out, int out_size, void* d_ws,
                              size_t ws_size, hipStream_t stream) {
  const float* x = (const float*)d_in[0];
  const int* rows = (const int*)d_in[1];
  const int* cols = (const int*)d_in[2];
  const float* vals = (const float*)d_in[3];
  const float* W1 = (const float*)d_in[4];
  const float* b1 = (const float*)d_in[5];
  const float* W2 = (const float*)d_in[6];
  const float* b2 = (const float*)d_in[7];
  float* out = (float*)d_out;

  char* ws = (char*)d_ws;
  const size_t HB_OFF = 0;                  // 12,800,000
  const size_t HA_OFF = 12800000;           // 12,800,000
  const size_t EDGES_OFF = 25600000;        // 12,800,000
  const size_t BREC_OFF = 38400000;         // 16,056,320
  const size_t ROWPTR_OFF = 54456320;       // 400,128
  const size_t BCUR_OFF = 54856448;         // 12,544
  const size_t W1T_OFF = 54870016;          // 65,536
  const size_t W2T_OFF = 54935552;          // 12,288  -> end 54,947,840

  __bf16* hA = (__bf16*)(ws + HA_OFF);
  __bf16* hB = (__bf16*)(ws + HB_OFF);
  u64* edges = (u64*)(ws + EDGES_OFF);
  u64* brec = (u64*)(ws + BREC_OFF);
  int* rowptr = (int*)(ws + ROWPTR_OFF);
  int* bcur = (int*)(ws + BCUR_OFF);
  __bf16* w1t = (__bf16*)(ws + W1T_OFF);
  __bf16* w2t = (__bf16*)(ws + W2T_OFF);

  (void)hipMemsetAsync(bcur, 0, NBUCK * 64, stream);

  pre_kernel<<<BUCKET_BLOCKS + CONVW_BLOCKS, 256, 0, stream>>>(
      W1, W2, w1t, w2t, rows, cols, vals, bcur, brec);

  fused_mlp_csr<<<MLP2_BLOCKS + NBUCK, 1024, 0, stream>>>(
      x, w1t, b1, w2t, b2, hA, bcur, brec, rowptr, edges);

  const int PROP_BLOCKS = (N_NODES * 64 + 255) / 256;
  for (int k = 0; k < K_STEPS - 1; k++) {
    const __bf16* hin = (k & 1) ? hB : hA;
    __bf16* hout = (k & 1) ? hA : hB;
    prop_kernel<0><<<PROP_BLOCKS, 256, 0, stream>>>(hin, hout, nullptr, rowptr,
                                                    edges);
  }
  prop_kernel<1><<<PROP_BLOCKS, 256, 0, stream>>>(hB, nullptr, out, rowptr,
                                                  edges);
}